// Round 8
// baseline (598.786 us; speedup 1.0000x reference)
//
#include <hip/hip_runtime.h>

#define TT 512
#define MM 8       // batch rows per block; grid 512 -> 2 independent blocks/CU

typedef _Float16 f16_t;
typedef f16_t f16x8 __attribute__((ext_vector_type(8)));
typedef float  f32x4 __attribute__((ext_vector_type(4)));

#define MFMA16(A, B, C) __builtin_amdgcn_mfma_f32_16x16x32_f16((A), (B), (C), 0, 0, 0)

__device__ __forceinline__ float fr(float x) { return __builtin_amdgcn_rcpf(x); }

#if __has_builtin(__builtin_amdgcn_exp2f)
__device__ __forceinline__ float ex2(float x) { return __builtin_amdgcn_exp2f(x); }
#define EXS 1.44269504f
#else
__device__ __forceinline__ float ex2(float x) { return __expf(x); }
#define EXS 1.0f
#endif

// LSTM cell: 5 exp + 3 rcp (numerics identical to R5-R7, absmax 2.441e-4).
// c' = (c*u + oa*(C-1)) / (oa*u), oa = 1+e^-f^, u = (1+e^-i^)(C+1), C = e^2g^.
// tanh(c') via 1-2/(E+1): E=inf -> 0 -> tanh=1 (c' is the only unbounded input).
// Biases pre-folded & scaled: bsc = { -EXS*bi, -EXS*bf, 2*EXS*bg, -EXS*bo }.
__device__ __forceinline__ float cellEW(float pi, float pf, float pg, float po,
                                        float4 bsc, float& c) {
    float A = ex2(fmaf(pf, -EXS, bsc.y));
    float B = ex2(fmaf(pi, -EXS, bsc.x));
    float C = ex2(fmaf(pg, 2.f * EXS, bsc.z));
    float oa = 1.f + A;
    float u  = (1.f + B) * (C + 1.f);
    float cn = fmaf(c, u, oa * (C - 1.f)) * fr(oa * u);
    c = cn;
    float D = ex2(fmaf(po, -EXS, bsc.w));
    float E = ex2(2.f * EXS * cn);
    return fr(1.f + D) * fmaf(-2.f, fr(E + 1.f), 1.f);
}

__device__ __forceinline__ f16x8 cvt8(const float* p) {
    f16x8 r;
#pragma unroll
    for (int e = 0; e < 8; ++e) r[e] = (f16_t)p[e];
    return r;
}

// x A-fragment: rows lc<8, k=0..3 (lq==0, e<4) valid, rest zero.
__device__ __forceinline__ f16x8 buildxf(float4 xq, int lq, int lc) {
    float v[4] = {xq.x, xq.y, xq.z, xq.w};
    f16x8 r;
#pragma unroll
    for (int e = 0; e < 8; ++e)
        r[e] = (e < 4 && lq == 0 && lc < 8) ? (f16_t)v[e] : (f16_t)0.f;
    return r;
}

// MFMA 16x16x32 f16 lane maps (verified R2-R7):
//   A[m][k]: lane l -> m = l%16, k = (l/16)*8 + e
//   B[k][n]: lane l -> n = l%16, k = (l/16)*8 + e
//   D[m][n]: lane l -> n = l%16, m = (l/16)*4 + q
// h-frag plane: f16 addr = kt*512 + chunk*8 + e; read chunk = l ^ (l>>4);
// write for h(m,k): lp = m + 16*((k&31)>>3), chunk = lp ^ ((k&31)>>3) (verified pair).
//
// Structure: 256 thr = 4 waves; wave wv owns h-tile wv (16 h-indices) for BOTH layers.
// Per step (1 barrier): a1 = gates1(t+1) [x(t+1) + h1(t)@W0^T], a2 = gates2(t)
// [h1(t)@W1^T + h2(t-1)@W2^T]. M=8: valid D rows live in lanes 0-31 only, so EW
// repacks: lane l handles layer (l>=32), rows rgrp*4+c (rgrp=(l>>4)&1), via
// tmp = shfl(a2[g][c], l&31); pre = (l<32) ? a1[g][c] : tmp  (reg idx compile-time).

__global__ __launch_bounds__(256, 2) void lstm_2b(
    const float* __restrict__ x,
    const float* __restrict__ w_ih0, const float* __restrict__ w_hh0,
    const float* __restrict__ b_ih0, const float* __restrict__ b_hh0,
    const float* __restrict__ w_ih1, const float* __restrict__ w_hh1,
    const float* __restrict__ b_ih1, const float* __restrict__ b_hh1,
    const float* __restrict__ fc1_w, const float* __restrict__ fc1_b,
    const float* __restrict__ fc2_w, const float* __restrict__ fc2_b,
    float* __restrict__ out)
{
    // planes 0,1 = h1 double-buffer; planes 2,3 = h2 double-buffer
    __shared__ __align__(16) unsigned hpl[4][512];
    __shared__ __align__(16) float sH[MM * 68];
    __shared__ float sY[MM * 34];

    const int tid = threadIdx.x;
    const int l   = tid & 63;
    const int wv  = tid >> 6;          // 0..3 = h-tile
    const int rbase = blockIdx.x * MM;

    const int lc = l & 15;
    const int lq = l >> 4;
    const int chunk = l ^ lq;
    const int hidx = wv * 16 + lc;

    // EW mapping
    const int rgrp = (l >> 4) & 1;     // row group 0/1
    const bool isl2 = (l >= 32);       // layer handled by this lane's EW
    // write-side addressing for h(m, hidx)
    const int ktw = hidx >> 5;
    const int kb  = (hidx & 31) >> 3;
    const int ew  = hidx & 7;

    // ---------------- prologue: both layers' B-fragments -> registers ----------------
    f16x8 wA0[4][2], wx[4], wA1[4][2], wB1[4][2];
    float4 bsc_ew;
    {
        float b0[4], b1[4];
#pragma unroll
        for (int g = 0; g < 4; ++g) {
            const int ga = g * 64 + hidx;
#pragma unroll
            for (int kt = 0; kt < 2; ++kt) {
                wA0[g][kt] = cvt8(w_hh0 + ga * 64 + kt * 32 + lq * 8);
                wA1[g][kt] = cvt8(w_ih1 + ga * 64 + kt * 32 + lq * 8);
                wB1[g][kt] = cvt8(w_hh1 + ga * 64 + kt * 32 + lq * 8);
            }
            float4 w4 = *(const float4*)(w_ih0 + ga * 4);
            float v[4] = {w4.x, w4.y, w4.z, w4.w};
#pragma unroll
            for (int e = 0; e < 8; ++e)
                wx[g][e] = (e < 4 && lq == 0) ? (f16_t)v[e] : (f16_t)0.f;
            b0[g] = b_ih0[ga] + b_hh0[ga];
            b1[g] = b_ih1[ga] + b_hh1[ga];
        }
        float bi = isl2 ? b1[0] : b0[0];
        float bf = isl2 ? b1[1] : b0[1];
        float bg = isl2 ? b1[2] : b0[2];
        float bo = isl2 ? b1[3] : b0[3];
        bsc_ew = make_float4(-EXS * bi, -EXS * bf, 2.f * EXS * bg, -EXS * bo);
    }

    for (int i = tid; i < 4 * 512; i += 256) ((unsigned*)hpl)[i] = 0;

    float c_st[4] = {0.f, 0.f, 0.f, 0.f};
    const f32x4 z4 = {0.f, 0.f, 0.f, 0.f};

    const float4* xg = (const float4*)x;
    const size_t xrow = (size_t)(rbase + (lc & 7)) * TT;
    float4 xq0 = xg[xrow + 0];
    float4 xq  = xg[xrow + 1];

    // stagger the co-resident partner block to seed MFMA/EW anti-phase
    if (blockIdx.x >= 256) __builtin_amdgcn_s_sleep(5);

    __syncthreads();

    // ---------------- prime: h1(0) from x(0) only -> plane 0 ----------------
    {
        f16x8 xf0 = buildxf(xq0, lq, lc);
        f32x4 ap[4];
#pragma unroll
        for (int g = 0; g < 4; ++g) ap[g] = MFMA16(xf0, wx[g], z4);
        if (l < 32) {                   // valid rows live here; these lanes are L1-EW lanes
            f16_t* dst = (f16_t*)hpl[0];
#pragma unroll
            for (int c = 0; c < 4; ++c) {
                float hv = cellEW(ap[0][c], ap[1][c], ap[2][c], ap[3][c], bsc_ew, c_st[c]);
                const int lp = (rgrp * 4 + c) + 16 * kb;
                dst[ktw * 512 + (lp ^ kb) * 8 + ew] = (f16_t)hv;
            }
        }
    }
    __syncthreads();

    // ---------------- main loop: 1 barrier/step ----------------
    int p = 0;
    for (int t = 0; t < TT; ++t) {
        const int tn = (t + 2 < TT) ? t + 2 : TT - 1;
        float4 xn = xg[xrow + tn];

        const f16_t* p1 = (const f16_t*)hpl[p];
        const f16_t* p2 = (const f16_t*)hpl[2 + p];
        f16x8 ah0 = *(const f16x8*)(p1 + chunk * 8);
        f16x8 ah1 = *(const f16x8*)(p1 + 512 + chunk * 8);
        f16x8 ph0 = *(const f16x8*)(p2 + chunk * 8);
        f16x8 ph1 = *(const f16x8*)(p2 + 512 + chunk * 8);
        f16x8 xf  = buildxf(xq, lq, lc);

        f32x4 a1[4], a2[4];
        __builtin_amdgcn_s_setprio(1);
#pragma unroll
        for (int g = 0; g < 4; ++g) {
            a1[g] = MFMA16(xf, wx[g], z4);
            a1[g] = MFMA16(ah0, wA0[g][0], a1[g]);
            a1[g] = MFMA16(ah1, wA0[g][1], a1[g]);
            a2[g] = MFMA16(ah0, wA1[g][0], z4);
            a2[g] = MFMA16(ah1, wA1[g][1], a2[g]);
            a2[g] = MFMA16(ph0, wB1[g][0], a2[g]);
            a2[g] = MFMA16(ph1, wB1[g][1], a2[g]);
        }
        __builtin_amdgcn_s_setprio(0);

        // repack: lane l takes layer (l>=32), rows rgrp*4+c, from lane l&31, reg c
        float pre[4][4];
#pragma unroll
        for (int g = 0; g < 4; ++g) {
#pragma unroll
            for (int c = 0; c < 4; ++c) {
                float tmp = __shfl(a2[g][c], l & 31);
                pre[g][c] = isl2 ? tmp : a1[g][c];
            }
        }

        f16_t* dst = (f16_t*)hpl[isl2 ? (2 + (p ^ 1)) : (p ^ 1)];
        const bool last = (t == TT - 1);
#pragma unroll
        for (int c = 0; c < 4; ++c) {
            float hv = cellEW(pre[0][c], pre[1][c], pre[2][c], pre[3][c], bsc_ew, c_st[c]);
            const int lp = (rgrp * 4 + c) + 16 * kb;
            dst[ktw * 512 + (lp ^ kb) * 8 + ew] = (f16_t)hv;
            if (last && isl2) sH[(rgrp * 4 + c) * 68 + hidx] = hv;
        }
        xq = xn;
        p ^= 1;
        __syncthreads();
    }

    // ---------------- FC head (8 rows, 256 threads) ----------------
    {
        const int r = tid >> 5, mo = tid & 31;   // exactly 8*32 = 256
        float s = fc1_b[mo];
#pragma unroll 8
        for (int k = 0; k < 64; ++k) s = fmaf(sH[r * 68 + k], fc1_w[mo * 64 + k], s);
        sY[r * 34 + mo] = fmaxf(s, 0.f);
    }
    __syncthreads();
    if (tid < MM * 2) {
        const int r = tid >> 1, o = tid & 1;
        float s = fc2_b[o];
#pragma unroll 8
        for (int mo = 0; mo < 32; ++mo) s = fmaf(sY[r * 34 + mo], fc2_w[o * 32 + mo], s);
        out[(size_t)(rbase + r) * 2 + o] = fmaxf(s, 0.f);
    }
}

extern "C" void kernel_launch(void* const* d_in, const int* in_sizes, int n_in,
                              void* d_out, int out_size, void* d_ws, size_t ws_size,
                              hipStream_t stream) {
    const float* x     = (const float*)d_in[0];
    const float* w_ih0 = (const float*)d_in[1];
    const float* w_hh0 = (const float*)d_in[2];
    const float* b_ih0 = (const float*)d_in[3];
    const float* b_hh0 = (const float*)d_in[4];
    const float* w_ih1 = (const float*)d_in[5];
    const float* w_hh1 = (const float*)d_in[6];
    const float* b_ih1 = (const float*)d_in[7];
    const float* b_hh1 = (const float*)d_in[8];
    const float* fc1_w = (const float*)d_in[9];
    const float* fc1_b = (const float*)d_in[10];
    const float* fc2_w = (const float*)d_in[11];
    const float* fc2_b = (const float*)d_in[12];
    float* out = (float*)d_out;

    const int nB   = in_sizes[0] / (TT * 4);   // 4096 rows
    const int grid = nB / MM;                  // 512 blocks -> 2 per CU

    lstm_2b<<<grid, 256, 0, stream>>>(x, w_ih0, w_hh0, b_ih0, b_hh0,
                                      w_ih1, w_hh1, b_ih1, b_hh1,
                                      fc1_w, fc1_b, fc2_w, fc2_b, out);
}

// Round 10
// 404.079 us; speedup vs baseline: 1.4819x; 1.4819x over previous
//
#include <hip/hip_runtime.h>

#define TT 512
#define MM 16      // batch rows per block; grid 256 = 1 block/CU (min-work shape)

typedef _Float16 f16_t;
typedef f16_t f16x8 __attribute__((ext_vector_type(8)));
typedef float  f32x4 __attribute__((ext_vector_type(4)));

#define MFMA16(A, B, C) __builtin_amdgcn_mfma_f32_16x16x32_f16((A), (B), (C), 0, 0, 0)

__device__ __forceinline__ float fr(float x) { return __builtin_amdgcn_rcpf(x); }

#if __has_builtin(__builtin_amdgcn_exp2f)
__device__ __forceinline__ float ex2(float x) { return __builtin_amdgcn_exp2f(x); }
#define EXS 1.44269504f
#else
__device__ __forceinline__ float ex2(float x) { return __expf(x); }
#define EXS 1.0f
#endif

#if __has_builtin(__builtin_amdgcn_cvt_pkrtz)
__device__ __forceinline__ unsigned pk2(float a, float b) {
    auto p = __builtin_amdgcn_cvt_pkrtz(a, b);   // __fp16 ext_vector(2)
    return __builtin_bit_cast(unsigned, p);
}
#else
__device__ __forceinline__ unsigned pk2(float a, float b) {
    unsigned short ha = __builtin_bit_cast(unsigned short, (f16_t)a);
    unsigned short hb = __builtin_bit_cast(unsigned short, (f16_t)b);
    return (unsigned)ha | ((unsigned)hb << 16);
}
#endif

// LSTM cell, 7 trans (5 ex2 + 2 rcp), NaN-safe:
//   c' = (c*u + oa*(C-1)) * rcp(oa*u);  oa = 1+e^-f^, u = (1+e^-i^)(C+1), C = e^2g^
//   h  = (E-1) * rcp((1+D)(E+1)),  E = 2^min(2*EXS*c', 30)  (clamp keeps E finite;
//        D=inf -> rcp=0 -> h=0 = correct sigma(o)->0 limit; E->0 -> h=-sigma(o) ok)
// Biases pre-folded & scaled: bq = { -EXS*bi, -EXS*bf, 2*EXS*bg, -EXS*bo }.
__device__ __forceinline__ float cellEW(float pi, float pf, float pg, float po,
                                        float4 bq, float& c) {
    float A = ex2(fmaf(pf, -EXS, bq.y));
    float B = ex2(fmaf(pi, -EXS, bq.x));
    float C = ex2(fmaf(pg, 2.f * EXS, bq.z));
    float oa = 1.f + A;
    float u  = (1.f + B) * (C + 1.f);
    float cn = fmaf(c, u, oa * (C - 1.f)) * fr(oa * u);
    c = cn;
    float D = ex2(fmaf(po, -EXS, bq.w));
    float E = ex2(fminf(2.f * EXS * cn, 30.f));
    return (E - 1.f) * fr((1.f + D) * (E + 1.f));
}

__device__ __forceinline__ f16x8 cvt8(const float* p) {
    f16x8 r;
#pragma unroll
    for (int e = 0; e < 8; ++e) r[e] = (f16_t)p[e];
    return r;
}

// x B-fragment: rows = all 16 (n = lc); k = 0..3 valid only (lq==0, e<4).
__device__ __forceinline__ f16x8 buildxf(float4 xq, int lq) {
    float v[4] = {xq.x, xq.y, xq.z, xq.w};
    f16x8 r;
#pragma unroll
    for (int e = 0; e < 8; ++e) r[e] = (e < 4 && lq == 0) ? (f16_t)v[e] : (f16_t)0.f;
    return r;
}

// SWAPPED-OPERAND MFMA (all lane maps verified R2-R8, semantics renamed):
//   A (arg0) = weight tile:  A[m=gcol][k]: lane l -> gcol = tile + l%16, k = (l/16)*8+e
//   B (arg1) = h:            B[k][n=row]:  lane l -> row = l%16,        k = (l/16)*8+e
//   D:                       lane l -> row = l%16, gcol-in-tile = (l/16)*4+q
// => each lane's 4 acc regs (per gate g) are 4 CONSECUTIVE hcols of ONE row.
// h-plane [16 rows][64 hcols] f16, byte(row,hcol) = (row*128 + hcol*2) ^ ((row&7)<<4):
//   b128 reads: 64 distinct 16B blocks (conflict-free); b64 writes: 2-way (free).
// Wave roles: wv 0..3 = layer 2 (wsub=wv), wv 4..7 = layer 1 (wsub=wv-4); wave's
// gcols = g*64 + wsub*16 + lane-map. Layer-pipelined: L1 computes step t+1 while
// L2 computes step t (R5 schedule, 1 barrier/step).

__global__ __launch_bounds__(512, 2) void lstm_swp(
    const float* __restrict__ x,
    const float* __restrict__ w_ih0, const float* __restrict__ w_hh0,
    const float* __restrict__ b_ih0, const float* __restrict__ b_hh0,
    const float* __restrict__ w_ih1, const float* __restrict__ w_hh1,
    const float* __restrict__ b_ih1, const float* __restrict__ b_hh1,
    const float* __restrict__ fc1_w, const float* __restrict__ fc1_b,
    const float* __restrict__ fc2_w, const float* __restrict__ fc2_b,
    float* __restrict__ out)
{
    __shared__ __align__(16) unsigned h1p[2][512];   // h1 planes (double buffer), 2KB each
    __shared__ __align__(16) unsigned h2p[2][512];   // h2 planes
    __shared__ __align__(16) float sH[MM * 68];
    __shared__ float sY[MM * 34];

    const int tid = threadIdx.x;
    const int l   = tid & 63;
    const int wv  = tid >> 6;
    const int rbase = blockIdx.x * MM;

    const int lc = l & 15;           // row (B/D n-dim; A m-row within W tile)
    const int lq = l >> 4;           // k-chunk / D m-group
    const bool isL1 = (wv >= 4);
    const int wsub = wv & 3;
    const int hc0  = wsub * 16 + lq * 4;        // lane's first hcol (4 consecutive)
    const int swz  = (lc & 7) << 4;

    // plane byte offsets
    const int rdo0 = (lc * 128 + 0 * 64 + lq * 16) ^ swz;   // B-frag kt=0
    const int rdo1 = (lc * 128 + 1 * 64 + lq * 16) ^ swz;   // B-frag kt=1
    const int wro  = (lc * 128 + hc0 * 2) ^ swz;            // b64 h write

    // ---------------- prologue: weight A-fragments -> registers ----------------
    f16x8 wA[4][2];   // h1-contraction weights (L1: w_hh0 ; L2: w_ih1)
    f16x8 wB[4][2];   // L2 only: w_hh1
    f16x8 wx[4];      // L1 only: w_ih0 (k=0..3)
    float4 bq[4];     // per-cell pre-scaled biases
#pragma unroll
    for (int g = 0; g < 4; ++g) {
        const int grow = (g * 64 + wsub * 16 + lc) * 64 + lq * 8;
        if (isL1) {
            wA[g][0] = cvt8(w_hh0 + grow);
            wA[g][1] = cvt8(w_hh0 + grow + 32);
            const int ga = (g * 64 + wsub * 16 + lc) * 4;
#pragma unroll
            for (int e = 0; e < 8; ++e)
                wx[g][e] = (e < 4 && lq == 0) ? (f16_t)w_ih0[ga + e] : (f16_t)0.f;
        } else {
            wA[g][0] = cvt8(w_ih1 + grow);
            wA[g][1] = cvt8(w_ih1 + grow + 32);
            wB[g][0] = cvt8(w_hh1 + grow);
            wB[g][1] = cvt8(w_hh1 + grow + 32);
        }
    }
#pragma unroll
    for (int q = 0; q < 4; ++q) {
        const int hc = hc0 + q;
        float b[4];
#pragma unroll
        for (int g = 0; g < 4; ++g) {
            const int ga = g * 64 + hc;
            b[g] = isL1 ? (b_ih0[ga] + b_hh0[ga]) : (b_ih1[ga] + b_hh1[ga]);
        }
        bq[q] = make_float4(-EXS * b[0], -EXS * b[1], 2.f * EXS * b[2], -EXS * b[3]);
    }

    float c_st[4] = {0.f, 0.f, 0.f, 0.f};
    const f32x4 z4 = {0.f, 0.f, 0.f, 0.f};

    const float4* xg = (const float4*)x;
    const size_t xrow = (size_t)(rbase + lc) * TT;
    float4 xq0 = make_float4(0, 0, 0, 0), xq = make_float4(0, 0, 0, 0);
    if (isL1) { xq0 = xg[xrow + 0]; xq = xg[xrow + 1]; }

    // ---------------- prime: L1 -> h1(0); L2 -> zero h2 plane 0 ----------------
    if (isL1) {
        f16x8 xf = buildxf(xq0, lq);
        f32x4 a[4];
#pragma unroll
        for (int g = 0; g < 4; ++g) a[g] = MFMA16(wx[g], xf, z4);
        float hv[4];
#pragma unroll
        for (int q = 0; q < 4; ++q)
            hv[q] = cellEW(a[0][q], a[1][q], a[2][q], a[3][q], bq[q], c_st[q]);
        uint2 w2 = make_uint2(pk2(hv[0], hv[1]), pk2(hv[2], hv[3]));
        *(uint2*)((char*)h1p[0] + wro) = w2;
    } else {
        h2p[0][tid] = 0;                // L2 waves = tid 0..255
        h2p[0][256 + tid] = 0;
    }
    __syncthreads();

    // ---------------- main loop: 1 barrier/step ----------------
    int p = 0;
    for (int t = 0; t < TT; ++t) {
        if (isL1) {
            if (t + 1 < TT) {
                const char* pl = (const char*)h1p[p];
                f16x8 hf0 = *(const f16x8*)(pl + rdo0);
                f16x8 hf1 = *(const f16x8*)(pl + rdo1);
                const int tn = (t + 2 < TT) ? t + 2 : TT - 1;
                float4 xn = xg[xrow + tn];
                f16x8 xf = buildxf(xq, lq);

                f32x4 a[4];
                __builtin_amdgcn_s_setprio(1);
#pragma unroll
                for (int g = 0; g < 4; ++g) {
                    a[g] = MFMA16(wx[g], xf, z4);
                    a[g] = MFMA16(wA[g][0], hf0, a[g]);
                    a[g] = MFMA16(wA[g][1], hf1, a[g]);
                }
                __builtin_amdgcn_s_setprio(0);

                float hv[4];
#pragma unroll
                for (int q = 0; q < 4; ++q)
                    hv[q] = cellEW(a[0][q], a[1][q], a[2][q], a[3][q], bq[q], c_st[q]);
                uint2 w2 = make_uint2(pk2(hv[0], hv[1]), pk2(hv[2], hv[3]));
                *(uint2*)((char*)h1p[p ^ 1] + wro) = w2;
                xq = xn;
            }
        } else {
            const char* pl1 = (const char*)h1p[p];
            const char* pl2 = (const char*)h2p[p];
            f16x8 hf0 = *(const f16x8*)(pl1 + rdo0);
            f16x8 hf1 = *(const f16x8*)(pl1 + rdo1);
            f16x8 gf0 = *(const f16x8*)(pl2 + rdo0);
            f16x8 gf1 = *(const f16x8*)(pl2 + rdo1);

            f32x4 a[4];
            __builtin_amdgcn_s_setprio(1);
#pragma unroll
            for (int g = 0; g < 4; ++g) {
                a[g] = MFMA16(wA[g][0], hf0, z4);
                a[g] = MFMA16(wA[g][1], hf1, a[g]);
                a[g] = MFMA16(wB[g][0], gf0, a[g]);
                a[g] = MFMA16(wB[g][1], gf1, a[g]);
            }
            __builtin_amdgcn_s_setprio(0);

            float hv[4];
#pragma unroll
            for (int q = 0; q < 4; ++q)
                hv[q] = cellEW(a[0][q], a[1][q], a[2][q], a[3][q], bq[q], c_st[q]);
            uint2 w2 = make_uint2(pk2(hv[0], hv[1]), pk2(hv[2], hv[3]));
            *(uint2*)((char*)h2p[p ^ 1] + wro) = w2;
            if (t == TT - 1)
                *(float4*)&sH[lc * 68 + hc0] = make_float4(hv[0], hv[1], hv[2], hv[3]);
        }
        p ^= 1;
        __syncthreads();
    }

    // ---------------- FC head ----------------
    {
        const int r = tid >> 5, mo = tid & 31;
        float s = fc1_b[mo];
#pragma unroll 8
        for (int k = 0; k < 64; ++k) s = fmaf(sH[r * 68 + k], fc1_w[mo * 64 + k], s);
        sY[r * 34 + mo] = fmaxf(s, 0.f);
    }
    __syncthreads();
    if (tid < 32) {
        const int r = tid >> 1, o = tid & 1;
        float s = fc2_b[o];
#pragma unroll 8
        for (int mo = 0; mo < 32; ++mo) s = fmaf(sY[r * 34 + mo], fc2_w[o * 32 + mo], s);
        out[(size_t)(rbase + r) * 2 + o] = fmaxf(s, 0.f);
    }
}

extern "C" void kernel_launch(void* const* d_in, const int* in_sizes, int n_in,
                              void* d_out, int out_size, void* d_ws, size_t ws_size,
                              hipStream_t stream) {
    const float* x     = (const float*)d_in[0];
    const float* w_ih0 = (const float*)d_in[1];
    const float* w_hh0 = (const float*)d_in[2];
    const float* b_ih0 = (const float*)d_in[3];
    const float* b_hh0 = (const float*)d_in[4];
    const float* w_ih1 = (const float*)d_in[5];
    const float* w_hh1 = (const float*)d_in[6];
    const float* b_ih1 = (const float*)d_in[7];
    const float* b_hh1 = (const float*)d_in[8];
    const float* fc1_w = (const float*)d_in[9];
    const float* fc1_b = (const float*)d_in[10];
    const float* fc2_w = (const float*)d_in[11];
    const float* fc2_b = (const float*)d_in[12];
    float* out = (float*)d_out;

    const int nB   = in_sizes[0] / (TT * 4);   // 4096 rows
    const int grid = nB / MM;                  // 256 blocks -> 1/CU

    lstm_swp<<<grid, 512, 0, stream>>>(x, w_ih0, w_hh0, b_ih0, b_hh0,
                                       w_ih1, w_hh1, b_ih1, b_hh1,
                                       fc1_w, fc1_b, fc2_w, fc2_b, out);
}

// Round 11
// 370.222 us; speedup vs baseline: 1.6174x; 1.0915x over previous
//
#include <hip/hip_runtime.h>

#define TT 512
#define MM 16      // batch rows per block; grid 256 = 1 block/CU (min-work shape)

typedef _Float16 f16_t;
typedef f16_t f16x8 __attribute__((ext_vector_type(8)));
typedef float  f32x4 __attribute__((ext_vector_type(4)));
typedef unsigned uintx4 __attribute__((ext_vector_type(4)));

#define MFMA16(A, B, C) __builtin_amdgcn_mfma_f32_16x16x32_f16((A), (B), (C), 0, 0, 0)

__device__ __forceinline__ float fr(float x) { return __builtin_amdgcn_rcpf(x); }

#if __has_builtin(__builtin_amdgcn_exp2f)
__device__ __forceinline__ float ex2(float x) { return __builtin_amdgcn_exp2f(x); }
#define EXS 1.44269504f
#else
__device__ __forceinline__ float ex2(float x) { return __expf(x); }
#define EXS 1.0f
#endif

#if __has_builtin(__builtin_amdgcn_cvt_pkrtz)
__device__ __forceinline__ unsigned pk2(float a, float b) {
    auto p = __builtin_amdgcn_cvt_pkrtz(a, b);   // __fp16 ext_vector(2)
    return __builtin_bit_cast(unsigned, p);
}
#else
__device__ __forceinline__ unsigned pk2(float a, float b) {
    unsigned short ha = __builtin_bit_cast(unsigned short, (f16_t)a);
    unsigned short hb = __builtin_bit_cast(unsigned short, (f16_t)b);
    return (unsigned)ha | ((unsigned)hb << 16);
}
#endif

// barrier: LDS-only wait (x loads are lane-private; no vmcnt drain needed).
// memory-clobber asms pin LDS stores before / loads after the barrier.
__device__ __forceinline__ void bar() {
    asm volatile("s_waitcnt lgkmcnt(0)" ::: "memory");
    __builtin_amdgcn_s_barrier();
    asm volatile("" ::: "memory");
}

// LSTM cell, 7 trans (5 ex2 + 2 rcp), NaN-safe (identical math to R10):
//   c' = (c*u + oa*(C-1)) * rcp(oa*u);  oa = 1+e^-f^, u = (1+e^-i^)(C+1), C = e^2g^
//   h  = (E-1) * rcp((1+D)(E+1)),  E = 2^min(2*EXS*c', 30)
// Biases pre-folded & scaled: bq = { -EXS*bi, -EXS*bf, 2*EXS*bg, -EXS*bo }.
__device__ __forceinline__ float cellEW(float pi, float pf, float pg, float po,
                                        float4 bq, float& c) {
    float A = ex2(fmaf(pf, -EXS, bq.y));
    float B = ex2(fmaf(pi, -EXS, bq.x));
    float C = ex2(fmaf(pg, 2.f * EXS, bq.z));
    float oa = 1.f + A;
    float u  = (1.f + B) * (C + 1.f);
    float cn = fmaf(c, u, oa * (C - 1.f)) * fr(oa * u);
    c = cn;
    float D = ex2(fmaf(po, -EXS, bq.w));
    float E = ex2(fminf(2.f * EXS * cn, 30.f));
    return (E - 1.f) * fr((1.f + D) * (E + 1.f));
}

__device__ __forceinline__ f16x8 cvt8(const float* p) {
    f16x8 r;
#pragma unroll
    for (int e = 0; e < 8; ++e) r[e] = (f16_t)p[e];
    return r;
}

// SWAPPED-OPERAND MFMA (verified R10):
//   A (arg0) = weight tile:  lane l -> gcol = tile + l%16, k = (l/16)*8+e
//   B (arg1) = h:            lane l -> row  = l%16,        k = (l/16)*8+e
//   D:                       lane l -> row  = l%16, gcol-in-tile = (l/16)*4+q
// h-plane [16 rows][64 hcols] f16, byte(row,hcol) = (row*128 + hcol*2) ^ ((row&7)<<4).
// Wave roles: wv 0..3 = layer 2, wv 4..7 = layer 1 (layer-pipelined, 1 barrier/step).

__global__ __launch_bounds__(512, 2) void lstm_v11(
    const float* __restrict__ x,
    const float* __restrict__ w_ih0, const float* __restrict__ w_hh0,
    const float* __restrict__ b_ih0, const float* __restrict__ b_hh0,
    const float* __restrict__ w_ih1, const float* __restrict__ w_hh1,
    const float* __restrict__ b_ih1, const float* __restrict__ b_hh1,
    const float* __restrict__ fc1_w, const float* __restrict__ fc1_b,
    const float* __restrict__ fc2_w, const float* __restrict__ fc2_b,
    float* __restrict__ out)
{
    __shared__ __align__(16) unsigned h1p[2][512];   // h1 planes (double buffer)
    __shared__ __align__(16) unsigned h2p[2][512];   // h2 planes
    __shared__ __align__(16) float sH[MM * 68];
    __shared__ float sY[MM * 34];

    const int tid = threadIdx.x;
    const int l   = tid & 63;
    const int wv  = tid >> 6;
    const int rbase = blockIdx.x * MM;

    const int lc = l & 15;
    const int lq = l >> 4;
    const bool isL1 = (wv >= 4);
    const int wsub = wv & 3;
    const int hc0  = wsub * 16 + lq * 4;
    const int swz  = (lc & 7) << 4;

    const int rdo0 = (lc * 128 + 0 * 64 + lq * 16) ^ swz;
    const int rdo1 = (lc * 128 + 1 * 64 + lq * 16) ^ swz;
    const int wro  = (lc * 128 + hc0 * 2) ^ swz;
    const unsigned xmask = (lq == 0) ? 0xFFFFFFFFu : 0u;

    // ---------------- prologue: weight A-fragments -> registers ----------------
    f16x8 wA[4][2];   // L1: w_hh0 ; L2: w_ih1
    f16x8 wB[4][2];   // L2 only: w_hh1
    f16x8 wx[4];      // L1 only: w_ih0 (k=0..3)
    float4 bq[4];
#pragma unroll
    for (int g = 0; g < 4; ++g) {
        const int grow = (g * 64 + wsub * 16 + lc) * 64 + lq * 8;
        if (isL1) {
            wA[g][0] = cvt8(w_hh0 + grow);
            wA[g][1] = cvt8(w_hh0 + grow + 32);
            const int ga = (g * 64 + wsub * 16 + lc) * 4;
#pragma unroll
            for (int e = 0; e < 8; ++e)
                wx[g][e] = (e < 4 && lq == 0) ? (f16_t)w_ih0[ga + e] : (f16_t)0.f;
        } else {
            wA[g][0] = cvt8(w_ih1 + grow);
            wA[g][1] = cvt8(w_ih1 + grow + 32);
            wB[g][0] = cvt8(w_hh1 + grow);
            wB[g][1] = cvt8(w_hh1 + grow + 32);
        }
    }
#pragma unroll
    for (int q = 0; q < 4; ++q) {
        const int hc = hc0 + q;
        float b[4];
#pragma unroll
        for (int g = 0; g < 4; ++g) {
            const int ga = g * 64 + hc;
            b[g] = isL1 ? (b_ih0[ga] + b_hh0[ga]) : (b_ih1[ga] + b_hh1[ga]);
        }
        bq[q] = make_float4(-EXS * b[0], -EXS * b[1], 2.f * EXS * b[2], -EXS * b[3]);
    }

    float c_st[4] = {0.f, 0.f, 0.f, 0.f};
    const f32x4 z4 = {0.f, 0.f, 0.f, 0.f};

    const float4* xg = (const float4*)x;
    const size_t xrow = (size_t)(rbase + lc) * TT;
    float4 xq = make_float4(0, 0, 0, 0);
    const float4* xp = xg + xrow + 2;          // next prefetch target = x(2)
    if (isL1) xq = xg[xrow + 1];               // x(t+1) at loop entry (t=0)

    // ---------------- prime: L1 -> h1(0); L2 -> zero h2 plane 0 ----------------
    if (isL1) {
        float4 x0 = xg[xrow + 0];
        unsigned a0 = pk2(x0.x, x0.y) & xmask, a1 = pk2(x0.z, x0.w) & xmask;
        uintx4 uv = {a0, a1, 0u, 0u};
        f16x8 xf = __builtin_bit_cast(f16x8, uv);
        f32x4 a[4];
#pragma unroll
        for (int g = 0; g < 4; ++g) a[g] = MFMA16(wx[g], xf, z4);
        float hv[4];
#pragma unroll
        for (int q = 0; q < 4; ++q)
            hv[q] = cellEW(a[0][q], a[1][q], a[2][q], a[3][q], bq[q], c_st[q]);
        uint2 w2 = make_uint2(pk2(hv[0], hv[1]), pk2(hv[2], hv[3]));
        *(uint2*)((char*)h1p[0] + wro) = w2;
    } else {
        h2p[0][tid] = 0;
        h2p[0][256 + tid] = 0;
    }
    __syncthreads();

    // ---------------- step body (planes hardcoded via args; flags fold at compile time) ----
    auto STEP = [&](const unsigned* h1r, unsigned* h1w,
                    const unsigned* h2r, unsigned* h2w,
                    bool l1act, bool pref, bool lastStore) {
        if (isL1) {
            if (l1act) {
                const char* pl = (const char*)h1r;
                f16x8 hf0 = *(const f16x8*)(pl + rdo0);
                f16x8 hf1 = *(const f16x8*)(pl + rdo1);
                float4 xn;
                if (pref) { xn = *xp; ++xp; }
                unsigned a0 = pk2(xq.x, xq.y) & xmask, a1 = pk2(xq.z, xq.w) & xmask;
                uintx4 uv = {a0, a1, 0u, 0u};
                f16x8 xf = __builtin_bit_cast(f16x8, uv);

                f32x4 a[4];
                __builtin_amdgcn_s_setprio(1);
#pragma unroll
                for (int g = 0; g < 4; ++g) {
                    a[g] = MFMA16(wx[g], xf, z4);
                    a[g] = MFMA16(wA[g][0], hf0, a[g]);
                    a[g] = MFMA16(wA[g][1], hf1, a[g]);
                }
                __builtin_amdgcn_s_setprio(0);

                float hv[4];
#pragma unroll
                for (int q = 0; q < 4; ++q)
                    hv[q] = cellEW(a[0][q], a[1][q], a[2][q], a[3][q], bq[q], c_st[q]);
                uint2 w2 = make_uint2(pk2(hv[0], hv[1]), pk2(hv[2], hv[3]));
                *(uint2*)((char*)h1w + wro) = w2;
                if (pref) xq = xn;
            }
        } else {
            const char* pl1 = (const char*)h1r;
            const char* pl2 = (const char*)h2r;
            f16x8 hf0 = *(const f16x8*)(pl1 + rdo0);
            f16x8 hf1 = *(const f16x8*)(pl1 + rdo1);
            f16x8 gf0 = *(const f16x8*)(pl2 + rdo0);
            f16x8 gf1 = *(const f16x8*)(pl2 + rdo1);

            f32x4 a[4];
            __builtin_amdgcn_s_setprio(1);
#pragma unroll
            for (int g = 0; g < 4; ++g) {
                a[g] = MFMA16(wA[g][0], hf0, z4);
                a[g] = MFMA16(wA[g][1], hf1, a[g]);
                a[g] = MFMA16(wB[g][0], gf0, a[g]);
                a[g] = MFMA16(wB[g][1], gf1, a[g]);
            }
            __builtin_amdgcn_s_setprio(0);

            float hv[4];
#pragma unroll
            for (int q = 0; q < 4; ++q)
                hv[q] = cellEW(a[0][q], a[1][q], a[2][q], a[3][q], bq[q], c_st[q]);
            uint2 w2 = make_uint2(pk2(hv[0], hv[1]), pk2(hv[2], hv[3]));
            *(uint2*)((char*)h2w + wro) = w2;
            if (lastStore)
                *(float4*)&sH[lc * 68 + hc0] = make_float4(hv[0], hv[1], hv[2], hv[3]);
        }
        bar();
    };

    // ---------------- main loop: t = 0..509, unrolled x2, no conditionals ----------------
    for (int it = 0; it < 255; ++it) {
        STEP(h1p[0], h1p[1], h2p[0], h2p[1], true, true, false);   // even t
        STEP(h1p[1], h1p[0], h2p[1], h2p[0], true, true, false);   // odd t
    }
    // t = 510: L1 computes gates1(511) (xq = x(511), no prefetch); L2 computes h2(510)
    STEP(h1p[0], h1p[1], h2p[0], h2p[1], true, false, false);
    // t = 511: L2 only -> h2(511) + sH
    STEP(h1p[1], h1p[0], h2p[1], h2p[0], false, false, true);

    // ---------------- FC head ----------------
    {
        const int r = tid >> 5, mo = tid & 31;
        float s = fc1_b[mo];
#pragma unroll 8
        for (int k = 0; k < 64; ++k) s = fmaf(sH[r * 68 + k], fc1_w[mo * 64 + k], s);
        sY[r * 34 + mo] = fmaxf(s, 0.f);
    }
    __syncthreads();
    if (tid < 32) {
        const int r = tid >> 1, o = tid & 1;
        float s = fc2_b[o];
#pragma unroll 8
        for (int mo = 0; mo < 32; ++mo) s = fmaf(sY[r * 34 + mo], fc2_w[o * 32 + mo], s);
        out[(size_t)(rbase + r) * 2 + o] = fmaxf(s, 0.f);
    }
}

extern "C" void kernel_launch(void* const* d_in, const int* in_sizes, int n_in,
                              void* d_out, int out_size, void* d_ws, size_t ws_size,
                              hipStream_t stream) {
    const float* x     = (const float*)d_in[0];
    const float* w_ih0 = (const float*)d_in[1];
    const float* w_hh0 = (const float*)d_in[2];
    const float* b_ih0 = (const float*)d_in[3];
    const float* b_hh0 = (const float*)d_in[4];
    const float* w_ih1 = (const float*)d_in[5];
    const float* w_hh1 = (const float*)d_in[6];
    const float* b_ih1 = (const float*)d_in[7];
    const float* b_hh1 = (const float*)d_in[8];
    const float* fc1_w = (const float*)d_in[9];
    const float* fc1_b = (const float*)d_in[10];
    const float* fc2_w = (const float*)d_in[11];
    const float* fc2_b = (const float*)d_in[12];
    float* out = (float*)d_out;

    const int nB   = in_sizes[0] / (TT * 4);   // 4096 rows
    const int grid = nB / MM;                  // 256 blocks -> 1/CU

    lstm_v11<<<grid, 512, 0, stream>>>(x, w_ih0, w_hh0, b_ih0, b_hh0,
                                       w_ih1, w_hh1, b_ih1, b_hh1,
                                       fc1_w, fc1_b, fc2_w, fc2_b, out);
}